// Round 7
// baseline (176.840 us; speedup 1.0000x reference)
//
#include <hip/hip_runtime.h>
#include <hip/hip_bf16.h>
#include <stdint.h>

#define N_SPK 2048
#define UU 32
#define DD 256
#define HALF_U 16
#define M_ROWS (N_SPK * HALF_U)   // 32768 test rows

typedef __attribute__((ext_vector_type(4))) float f32x4;
typedef __attribute__((ext_vector_type(2))) long long2_t;   // 16 B

// ---------------- prep: centroids + normalize -> fp8 e4m3, fragment-major --
// Row layout permutation: byte for k goes to pos = t*64 + hi*16 + half*8 + i
// where k = (2t+half)*32 + hi*8 + i. A lane's 16B load at (row, t, hi) then
// yields the two k-fragments (kk=2t lo 8B, kk=2t+1 hi 8B) for MFMA lane
// (row=l&15, hi=l>>4) -- and 4 hi-lanes cover a dense 64B line.
__global__ __launch_bounds__(256) void prep_kernel(const float* __restrict__ emb,
                                                   uint8_t* __restrict__ tn8,
                                                   uint8_t* __restrict__ cn8,
                                                   float* __restrict__ zbuf)
{
    if (blockIdx.x == 0) {
        #pragma unroll
        for (int i = 0; i < 16; ++i) zbuf[threadIdx.x + 256 * i] = 0.0f;   // total+pos
    }

    const int w = threadIdx.x >> 6;
    const int l = threadIdx.x & 63;
    const int task = blockIdx.x * 4 + w;

    float4 v;
    if (task < M_ROWS) {
        const int m = task >> 4;
        const int t = task & 15;
        const size_t grow = (size_t)m * UU + HALF_U + t;
        v = *(const float4*)(emb + grow * DD + 4 * l);
    } else {
        const int n = task - M_ROWS;
        float ax = 0.f, ay = 0.f, az = 0.f, aw = 0.f;
        const float* base = emb + (size_t)n * UU * DD + 4 * l;
        #pragma unroll
        for (int j = 0; j < HALF_U; ++j) {
            float4 e = *(const float4*)(base + j * DD);
            ax += e.x; ay += e.y; az += e.z; aw += e.w;
        }
        const float inv = 1.0f / 16.0f;
        v = make_float4(ax * inv, ay * inv, az * inv, aw * inv);
    }
    float ss = v.x * v.x + v.y * v.y + v.z * v.z + v.w * v.w;
    #pragma unroll
    for (int d = 1; d < 64; d <<= 1) ss += __shfl_xor(ss, d);
    const float sc = 1.0f / fmaxf(sqrtf(ss), 1e-8f);

    // pack 4 contiguous elems d0..d0+3 (same fragment group since d0%4==0)
    int p = __builtin_amdgcn_cvt_pk_fp8_f32(v.x * sc, v.y * sc, 0, 0);
    p     = __builtin_amdgcn_cvt_pk_fp8_f32(v.z * sc, v.w * sc, p, 1);

    const int d0  = 4 * l;
    const int t4  = d0 >> 6;           // kk-pair
    const int hi4 = (d0 >> 3) & 3;     // lane k-group
    const int hf  = (d0 >> 5) & 1;     // which kk of the pair
    const int pos = t4 * 64 + hi4 * 16 + hf * 8 + (d0 & 7);

    uint8_t* dst = (task < M_ROWS)
        ? (tn8 + (size_t)task * DD + pos)
        : (cn8 + (size_t)(task - M_ROWS) * DD + pos);
    *(int*)dst = p;
}

// ---------------- fused GEMM: no LDS tiles, no main-loop barriers ---------
// 128x128 tile, 256 thr (4 waves 2x2, per-wave 64x64), full K=256 unrolled.
// A/B read directly from L1/L2 in fragment-major layout (16B/lane dense).
// 4 blocks/CU; compiler pipelines loads across MFMA (m97 mechanism).
__global__ __launch_bounds__(256, 4) void gemm_kernel(const uint8_t* __restrict__ tn8,
                                                      const uint8_t* __restrict__ cn8,
                                                      const float* __restrict__ alphaP,
                                                      const float* __restrict__ betaP,
                                                      float* __restrict__ total,
                                                      float* __restrict__ pos)
{
    __shared__ float csum[128];

    const int tid = threadIdx.x;
    const int l = tid & 63;
    const int w = tid >> 6;            // 0..3
    const int wr = w >> 1, wc = w & 1; // 2M x 2N; per-wave out 64x64
    const int r16 = l & 15, hi = l >> 4;

    // XCD swizzle: grid 4096 = 8 XCDs x 512; per XCD bm in [xcd*32,+32) x 16 bn
    const int bid = blockIdx.x;
    const int tile = (bid & 7) * 512 + (bid >> 3);
    const int bm = tile >> 4;          // 0..255
    const int bn = tile & 15;          // 0..15

    const uint8_t* Abase = tn8 + (size_t)(bm * 128 + wr * 64 + r16) * DD + hi * 16;
    const uint8_t* Bbase = cn8 + (size_t)(bn * 128 + wc * 64 + r16) * DD + hi * 16;

    f32x4 acc[4][4] = {};

    #pragma unroll
    for (int t = 0; t < 4; ++t) {      // kk-pair: covers k = t*64 .. t*64+63
        long2_t a2[4], b2[4];
        #pragma unroll
        for (int mi = 0; mi < 4; ++mi)
            a2[mi] = *(const long2_t*)(Abase + (size_t)mi * 16 * DD + t * 64);
        #pragma unroll
        for (int ni = 0; ni < 4; ++ni)
            b2[ni] = *(const long2_t*)(Bbase + (size_t)ni * 16 * DD + t * 64);
        #pragma unroll
        for (int mi = 0; mi < 4; ++mi)
            #pragma unroll
            for (int ni = 0; ni < 4; ++ni)
                acc[mi][ni] = __builtin_amdgcn_mfma_f32_16x16x32_fp8_fp8(
                    a2[mi][0], b2[ni][0], acc[mi][ni], 0, 0, 0);
        #pragma unroll
        for (int mi = 0; mi < 4; ++mi)
            #pragma unroll
            for (int ni = 0; ni < 4; ++ni)
                acc[mi][ni] = __builtin_amdgcn_mfma_f32_16x16x32_fp8_fp8(
                    a2[mi][1], b2[ni][1], acc[mi][ni], 0, 0, 0);
    }

    // ---- epilogue: exp, column sums, diagonal ----
    const float alpha = *alphaP;
    const float beta  = *betaP;
    const bool diag = ((bm >> 4) == bn);   // tile contains positive pairs

    if (tid < 128) csum[tid] = 0.0f;
    __syncthreads();

    #pragma unroll
    for (int ni = 0; ni < 4; ++ni) {
        const int colg = bn * 128 + wc * 64 + ni * 16 + r16;   // C/D: col = lane&15
        float cs = 0.f;
        #pragma unroll
        for (int mi = 0; mi < 4; ++mi) {
            const int rowbase = bm * 128 + wr * 64 + mi * 16 + hi * 4;  // row=(l>>4)*4+r
            #pragma unroll
            for (int r = 0; r < 4; ++r) {
                const float e = __expf(alpha * acc[mi][ni][r] + beta);
                cs += e;
                if (diag && ((rowbase + r) >> 4) == colg)     // positive pair
                    atomicAdd(pos + colg, e);
            }
        }
        cs += __shfl_xor(cs, 16);
        cs += __shfl_xor(cs, 32);
        if (hi == 0) atomicAdd(&csum[wc * 64 + ni * 16 + r16], cs);
    }
    __syncthreads();
    if (tid < 128) atomicAdd(total + bn * 128 + tid, csum[tid]);
}

// ---------------- finalize: loss = mean(log(tot-pos) - log(pos)) ----------
__global__ __launch_bounds__(256) void finalize_kernel(const float* __restrict__ total,
                                                       const float* __restrict__ pos,
                                                       float* __restrict__ out)
{
    const int tid = threadIdx.x;
    float s = 0.f;
    for (int i = tid; i < N_SPK; i += 256) {
        const float p = pos[i];
        const float t = total[i];
        s += logf(t - p) - logf(p);
    }
    #pragma unroll
    for (int d = 1; d < 64; d <<= 1) s += __shfl_xor(s, d);
    __shared__ float wsum[4];
    if ((tid & 63) == 0) wsum[tid >> 6] = s;
    __syncthreads();
    if (tid == 0) out[0] = (wsum[0] + wsum[1] + wsum[2] + wsum[3]) * (1.0f / (float)N_SPK);
}

extern "C" void kernel_launch(void* const* d_in, const int* in_sizes, int n_in,
                              void* d_out, int out_size, void* d_ws, size_t ws_size,
                              hipStream_t stream)
{
    const float* emb    = (const float*)d_in[0];
    const float* alphaP = (const float*)d_in[2];
    const float* betaP  = (const float*)d_in[3];
    float* out = (float*)d_out;

    char* ws = (char*)d_ws;
    uint8_t* tn8 = (uint8_t*)ws;                                   // 32768*256 = 8 MiB
    uint8_t* cn8 = (uint8_t*)(ws + 8388608);                       // 2048*256 = 512 KiB
    float* total = (float*)(ws + 8388608 + 524288);                // 2048 f32
    float* pos   = total + N_SPK;                                  // 2048 f32

    hipLaunchKernelGGL(prep_kernel, dim3((M_ROWS + N_SPK) / 4), dim3(256), 0, stream,
                       emb, tn8, cn8, total /* zeroes total+pos */);
    hipLaunchKernelGGL(gemm_kernel, dim3(M_ROWS / 128 * (N_SPK / 128)), dim3(256), 0, stream,
                       tn8, cn8, alphaP, betaP, total, pos);
    hipLaunchKernelGGL(finalize_kernel, dim3(1), dim3(256), 0, stream,
                       total, pos, out);
}